// Round 1
// 210.842 us; speedup vs baseline: 1.0065x; 1.0065x over previous
//
#include <hip/hip_runtime.h>

// SwappedPredictionLoss: Sinkhorn-Knopp (3 iters) + swapped cross-entropy.
//
// q[b,k] = B * e_bk * u_b * v_k,  e = exp(S/eps)
//   row-normalize: v_k = 1/(K*R_k),  R_k = sum_b e_bk * u_b
//   col-normalize: u_b = 1/(B*C_b),  C_b = sum_k e_bk * v_k
// loss = sum_pairs [ (1/B) sum_b lse_t[b] - sum_b u_b * sum_k e_s*v_k*(S_t/T) ]
// From e alone (eps/T = 0.5):  S/T = 0.5*ln(e),  exp(S/T) = sqrt(e).
//
// R4/R9/R10: cross-phase fusion with grid barriers loses. R5: hot global
// atomics banned. R11: per-thread stream widening falsified. R12: reduce
// kernels are CU-COUNT-bound (~25 GB/s/CU) -> spread over many CUs.
// R13 (this round): rowsum+colsum are CHUNK-LOCAL -> fuse per 16-row
// half-chunk (one block: row phase -> Ulds -> barrier -> col phase).
// E read once per iteration instead of twice; U never hits global;
// kernel count 10 -> 8. ~58us ws re-poison fill is in-window, irreducible.

#define NVIEWS 2
#define BATCH 4096
#define KPROTO 3000
#define KB 3072      // padded fp8 row stride (bytes); V row length (floats)
#define NT 256
#define RROWS 16     // rows per half-chunk (rc_kernel block granularity)
#define NPL 256      // planes per view = BATCH / RROWS
#define LOSS_BLOCKS 1024

constexpr float EPS_INV = 20.0f;  // 1/0.05
constexpr float KF = 3000.0f;
constexpr float BF = 4096.0f;

typedef float floatx2 __attribute__((ext_vector_type(2)));

__device__ __forceinline__ float fast_rcp(float x) { return __builtin_amdgcn_rcpf(x); }
__device__ __forceinline__ float fast_sqrt(float x) { return __builtin_amdgcn_sqrtf(x); }

__device__ __forceinline__ float wave_sum(float x) {
#pragma unroll
  for (int o = 32; o > 0; o >>= 1) x += __shfl_down(x, o, 64);
  return x;
}

__device__ __forceinline__ float4 dec4(unsigned u) {
  floatx2 lo = __builtin_amdgcn_cvt_pk_f32_fp8((int)u, false);
  floatx2 hi = __builtin_amdgcn_cvt_pk_f32_fp8((int)u, true);
  return make_float4(lo.x, lo.y, hi.x, hi.y);
}

__device__ __forceinline__ float dot4(float4 a, float4 b) {
  return a.x * b.x + a.y * b.y + a.z * b.z + a.w * b.w;
}

// P1: e = exp(S/eps); store fp8 E (pad=0); per-half-chunk column partials -> P.
// grid 1536: c = i&255 (16-row half-chunk), m = i>>8: v = m/3, sub = m%3.
__global__ __launch_bounds__(NT) void p1_kernel(const float* __restrict__ S,
                                                unsigned char* __restrict__ E,
                                                float* __restrict__ P) {
  const int i = blockIdx.x;
  const int c = i & 255;
  const int m = i >> 8;
  const int v = m / 3;
  const int sub = m - v * 3;
  const int f = sub * NT + threadIdx.x;  // 4-col group, 0..767
  const int b0 = c * RROWS;
  float4 acc = make_float4(0.f, 0.f, 0.f, 0.f);
  unsigned* Erow = (unsigned*)(E + ((size_t)v * BATCH + b0) * KB) + f;
  if (f < KPROTO / 4) {
    const float4* S4 = (const float4*)(S + ((size_t)v * BATCH + b0) * KPROTO) + f;
#pragma unroll 4
    for (int b = 0; b < RROWS; ++b) {
      float4 s = S4[(size_t)b * (KPROTO / 4)];
      float ex = __expf(s.x * EPS_INV), ey = __expf(s.y * EPS_INV);
      float ez = __expf(s.z * EPS_INV), ew = __expf(s.w * EPS_INV);
      acc.x += ex; acc.y += ey; acc.z += ez; acc.w += ew;
      int pk = __builtin_amdgcn_cvt_pk_fp8_f32(ex, ey, 0, false);
      pk = __builtin_amdgcn_cvt_pk_fp8_f32(ez, ew, pk, true);
      Erow[(size_t)b * (KB / 4)] = (unsigned)pk;
    }
  } else {
#pragma unroll 4
    for (int b = 0; b < RROWS; ++b) Erow[(size_t)b * (KB / 4)] = 0u;  // e=0 pad
  }
  ((float4*)(P + (size_t)(v * NPL + c) * KB))[f] = acc;
}

// Reduce: V[v][k] = 1/max(K * sum_y P[v][y][k], tiny).
// grid 192 (v*96+sub), block 256 = 32 ygroups x 8 cols; LDS folds ygroups.
// 192 CUs active, 32 KB/block (CU-count-bound regime, ~1.5 us).
__global__ __launch_bounds__(NT) void reduce_kernel(const float* __restrict__ P,
                                                    float* __restrict__ V) {
  __shared__ float4 sm[32][9];
  const int v = blockIdx.x / 96;
  const int sub = blockIdx.x - v * 96;
  const int cl = threadIdx.x & 7;
  const int yg = threadIdx.x >> 3;
  const int col4 = sub * 8 + cl;  // float4-column, 0..767
  const float4* base = (const float4*)(P + (size_t)v * NPL * KB) + col4;
  float4 a = make_float4(0.f, 0.f, 0.f, 0.f);
#pragma unroll
  for (int y = yg * 8; y < yg * 8 + 8; ++y) {
    float4 p = base[(size_t)y * (KB / 4)];
    a.x += p.x; a.y += p.y; a.z += p.z; a.w += p.w;
  }
  sm[yg][cl] = a;
  __syncthreads();
  if (yg == 0) {
    float4 s = sm[0][cl];
#pragma unroll
    for (int g = 1; g < 32; ++g) {
      float4 p = sm[g][cl];
      s.x += p.x; s.y += p.y; s.z += p.z; s.w += p.w;
    }
    float4 o;
    o.x = fast_rcp(fmaxf(s.x * KF, 1e-35f));
    o.y = fast_rcp(fmaxf(s.y * KF, 1e-35f));
    o.z = fast_rcp(fmaxf(s.z * KF, 1e-35f));
    o.w = fast_rcp(fmaxf(s.w * KF, 1e-35f));
    ((float4*)(V + v * KB))[col4] = o;
  }
}

// RC (fused rowsum+colsum, chunk-local): one block per 16-row half-chunk.
// Phase A: wave wv handles rows wv*4..wv*4+3; full-row dot e.V -> u -> Ulds.
// Phase B: 256 threads x 3 col-groups sum e*u over the 16 rows -> P plane.
// E chunk (48 KB) read from global once (phase B re-read hits L1/L2).
// grid 512: v = i>>8, h = i&255.
__global__ __launch_bounds__(NT) void rc_kernel(const unsigned char* __restrict__ E,
                                                const float* __restrict__ V,
                                                float* __restrict__ P) {
  __shared__ float Ulds[RROWS];
  const int i = blockIdx.x;
  const int v = i >> 8;
  const int h = i & 255;
  const int b0 = h * RROWS;
  const int wv = threadIdx.x >> 6, ln = threadIdx.x & 63;
  const float4* V4 = (const float4*)(V + v * KB);
  // Preload this lane's V fragment once; reused for 4 rows.
  float4 vv[3][4];
#pragma unroll
  for (int q = 0; q < 3; ++q) {
    const int f = q * 64 + ln;
#pragma unroll
    for (int j = 0; j < 4; ++j) vv[q][j] = V4[4 * f + j];
  }
  // Phase A: rowsum
#pragma unroll
  for (int rr = 0; rr < 4; ++rr) {
    const int row = wv * 4 + rr;
    const uint4* Erow = (const uint4*)(E + ((size_t)v * BATCH + b0 + row) * KB);
    float acc = 0.f;
#pragma unroll
    for (int q = 0; q < 3; ++q) {
      uint4 pk = Erow[q * 64 + ln];
      acc += dot4(dec4(pk.x), vv[q][0]) + dot4(dec4(pk.y), vv[q][1])
           + dot4(dec4(pk.z), vv[q][2]) + dot4(dec4(pk.w), vv[q][3]);
    }
    acc = wave_sum(acc);
    if (ln == 0) Ulds[row] = fast_rcp(acc * BF);
  }
  __syncthreads();
  // Phase B: colsum partials for this half-chunk
  const unsigned* Ecol = (const unsigned*)(E + ((size_t)v * BATCH + b0) * KB);
  float4* Pout = (float4*)(P + (size_t)(v * NPL + h) * KB);
#pragma unroll
  for (int q = 0; q < 3; ++q) {
    const int f = q * NT + threadIdx.x;  // 4-col group, 0..767
    float4 acc = make_float4(0.f, 0.f, 0.f, 0.f);
#pragma unroll 8
    for (int b = 0; b < RROWS; ++b) {
      float u = Ulds[b];
      float4 e = dec4(Ecol[(size_t)b * (KB / 4) + f]);
      acc.x += e.x * u; acc.y += e.y * u; acc.z += e.z * u; acc.w += e.w * u;
    }
    Pout[f] = acc;
  }
}

// Loss: one wave per row b; reads both views' E rows once. C3 inline (R7 shape).
// grid 1024: c = i&127, j = i>>7; b = c*32 + j*4 + wv.
__global__ __launch_bounds__(NT) void loss_kernel(const unsigned char* __restrict__ E,
                                                  const int* __restrict__ ci,
                                                  const int* __restrict__ si,
                                                  const float* __restrict__ V3,
                                                  float* __restrict__ part) {
  const int i = blockIdx.x;
  const int c = i & 127;
  const int j = i >> 7;
  const int wv = threadIdx.x >> 6, ln = threadIdx.x & 63;
  const int b = c * 32 + j * 4 + wv;
  const uint4* r0 = (const uint4*)(E + (size_t)b * KB);
  const uint4* r1 = (const uint4*)(E + ((size_t)BATCH + b) * KB);
  const float4* V0 = (const float4*)V3;
  const float4* V1 = (const float4*)(V3 + KB);
  float c0 = 0.f, c1 = 0.f, se0 = 0.f, se1 = 0.f;
  float cr00 = 0.f, cr01 = 0.f, cr10 = 0.f, cr11 = 0.f;
#pragma unroll
  for (int q = 0; q < 3; ++q) {
    const int f = q * 64 + ln;
    uint4 p0 = r0[f], p1 = r1[f];
#define GRP(pu0, pu1, idx)                                \
  {                                                       \
    float4 ea = dec4(pu0), eb = dec4(pu1);                \
    float4 va = V0[4 * f + idx], vb = V1[4 * f + idx];    \
    _Pragma("unroll") for (int t = 0; t < 4; ++t) {       \
      float e0r = (&ea.x)[t], e1r = (&eb.x)[t];           \
      float ev0 = e0r * (&va.x)[t];                       \
      float ev1 = e1r * (&vb.x)[t];                       \
      float st0 = 0.5f * __logf(fmaxf(e0r, 1e-30f));      \
      float st1 = 0.5f * __logf(fmaxf(e1r, 1e-30f));      \
      se0 += fast_sqrt(e0r);                              \
      se1 += fast_sqrt(e1r);                              \
      c0 += ev0; c1 += ev1;                               \
      cr00 += ev0 * st0; cr01 += ev0 * st1;               \
      cr10 += ev1 * st0; cr11 += ev1 * st1;               \
    }                                                     \
  }
    GRP(p0.x, p1.x, 0)
    GRP(p0.y, p1.y, 1)
    GRP(p0.z, p1.z, 2)
    GRP(p0.w, p1.w, 3)
#undef GRP
  }
  c0 = wave_sum(c0);   c1 = wave_sum(c1);
  se0 = wave_sum(se0); se1 = wave_sum(se1);
  cr00 = wave_sum(cr00); cr01 = wave_sum(cr01);
  cr10 = wave_sum(cr10); cr11 = wave_sum(cr11);
  __shared__ float sm[4];
  if (ln == 0) {
    const float cArr[2] = {c0, c1};
    const float seArr[2] = {se0, se1};
    const float cr[2][2] = {{cr00, cr01}, {cr10, cr11}};
    float loss = 0.f;
#pragma unroll
    for (int p = 0; p < 2; ++p) {
      const int s = ci[p] & 1;
      const int t = si[p] & 1;
      loss += __logf(seArr[t]) * (1.0f / BF) - cr[s][t] * fast_rcp(cArr[s] * BF);
    }
    sm[wv] = loss;
  }
  __syncthreads();
  if (threadIdx.x == 0) part[i] = sm[0] + sm[1] + sm[2] + sm[3];
}

__global__ void final_kernel(const float* __restrict__ part, float* __restrict__ out) {
  float a = 0.f;
  for (int i = threadIdx.x; i < LOSS_BLOCKS; i += NT) a += part[i];
  a = wave_sum(a);
  __shared__ float sm[4];
  const int ln = threadIdx.x & 63;
  const int w = threadIdx.x >> 6;
  if (ln == 0) sm[w] = a;
  __syncthreads();
  if (threadIdx.x == 0) out[0] = sm[0] + sm[1] + sm[2] + sm[3];
}

extern "C" void kernel_launch(void* const* d_in, const int* in_sizes, int n_in,
                              void* d_out, int out_size, void* d_ws, size_t ws_size,
                              hipStream_t stream) {
  const float* S = (const float*)d_in[0];
  const int* code_ids = (const int*)d_in[1];  // int32 on the wire
  const int* score_ids = (const int*)d_in[2];

  float* ws = (float*)d_ws;
  // ws (floats): V [2][KB] | part [1024] | P [2][NPL][KB] | E fp8
  float* V = ws;
  float* part = V + NVIEWS * KB;
  float* P = part + LOSS_BLOCKS;
  unsigned char* E = (unsigned char*)(P + (size_t)NVIEWS * NPL * KB);  // 16B-aligned

  dim3 blk(NT);
  p1_kernel<<<1536, blk, 0, stream>>>(S, E, P);
  reduce_kernel<<<192, blk, 0, stream>>>(P, V);
  rc_kernel<<<512, blk, 0, stream>>>(E, V, P);
  reduce_kernel<<<192, blk, 0, stream>>>(P, V);
  rc_kernel<<<512, blk, 0, stream>>>(E, V, P);
  reduce_kernel<<<192, blk, 0, stream>>>(P, V);
  loss_kernel<<<1024, blk, 0, stream>>>(E, code_ids, score_ids, V, part);
  final_kernel<<<1, blk, 0, stream>>>(part, (float*)d_out);
}